// Round 1
// baseline (772.084 us; speedup 1.0000x reference)
//
#include <hip/hip_runtime.h>
#include <stdint.h>

typedef __attribute__((ext_vector_type(8))) short short8;
typedef __attribute__((ext_vector_type(4))) float f4;
typedef unsigned short u16;

// Problem dims (fixed)
#define Nn 2048          // seq len
#define Dd 512           // model dim = DK = DV
#define Hh 8             // heads
#define BNrows 4096      // B*N
#define SCALE 0.044194173824159216f  // 1/sqrt(512)

// ---------- helpers ----------
__device__ __forceinline__ u16 f2b(float f) {   // f32 -> bf16 RNE
  union { float f; uint32_t u; } c; c.f = f;
  uint32_t u = c.u;
  u += 0x7fffu + ((u >> 16) & 1u);
  return (u16)(u >> 16);
}

__device__ __forceinline__ void gload_lds16(const void* g, void* l) {
  // async global->LDS, 16B per lane; LDS dest = wave-uniform base + lane*16
  __builtin_amdgcn_global_load_lds((const __attribute__((address_space(1))) void*)g,
                                   (__attribute__((address_space(3))) void*)l, 16, 0, 0);
}

// ---------- tiny kernels ----------
__global__ void cvt_kernel(const float* __restrict__ src, u16* __restrict__ dst, int n8) {
  int i = blockIdx.x * 256 + threadIdx.x;
  if (i >= n8) return;
  const f4* s4 = (const f4*)src;
  f4 a = s4[2*i], b = s4[2*i+1];
  short8 o;
  o[0]=(short)f2b(a[0]); o[1]=(short)f2b(a[1]); o[2]=(short)f2b(a[2]); o[3]=(short)f2b(a[3]);
  o[4]=(short)f2b(b[0]); o[5]=(short)f2b(b[1]); o[6]=(short)f2b(b[2]); o[7]=(short)f2b(b[3]);
  ((short8*)dst)[i] = o;
}

__global__ void zero_kernel(float* __restrict__ p, int n) {
  int i = blockIdx.x * 256 + threadIdx.x;
  if (i < n) p[i] = 0.0f;
}

__global__ void recip_kernel(const float* __restrict__ s, float* __restrict__ rs, int n) {
  int i = blockIdx.x * 256 + threadIdx.x;
  if (i < n) rs[i] = 1.0f / s[i];
}

// ---------- projection GEMM: C[m,n] = sum_k A[m,k]*B[n,k] + bias, bf16 out ----------
// 128x128 tile, BK=64, 4 waves (2x2 of 64x64), m97-style single-buffer LDS.
__launch_bounds__(256)
__global__ void proj_gemm(const u16* __restrict__ A, int lda,
                          const u16* __restrict__ Bm, int ldb,
                          const float* __restrict__ bias, int bias_row,
                          u16* __restrict__ C, int ldc) {
  __shared__ __align__(16) u16 Al[128*64];
  __shared__ __align__(16) u16 Bl[128*64];
  const int t = threadIdx.x, w = t >> 6, l = t & 63;
  const int m0 = blockIdx.y * 128, n0 = blockIdx.x * 128;
  const int wm = (w >> 1) * 64, wn = (w & 1) * 64;
  const int srow = l >> 3, scol = (l & 7) * 8;
  f4 acc[4][4] = {};
  for (int k0 = 0; k0 < 512; k0 += 64) {
    #pragma unroll
    for (int j = 0; j < 4; ++j) {
      const int chunk = (w << 2) + j;       // 16 chunks of 1KB per tile
      const int row = (chunk << 3) + srow;
      gload_lds16(A  + (size_t)(m0 + row) * lda + (k0 + scol), &Al[chunk << 9]);
      gload_lds16(Bm + (size_t)(n0 + row) * ldb + (k0 + scol), &Bl[chunk << 9]);
    }
    __syncthreads();
    #pragma unroll
    for (int ks = 0; ks < 64; ks += 32) {
      short8 af[4], bfr[4];
      #pragma unroll
      for (int i = 0; i < 4; ++i)
        af[i] = *(const short8*)&Al[(wm + i*16 + (l & 15)) * 64 + ks + ((l >> 4) << 3)];
      #pragma unroll
      for (int j = 0; j < 4; ++j)
        bfr[j] = *(const short8*)&Bl[(wn + j*16 + (l & 15)) * 64 + ks + ((l >> 4) << 3)];
      #pragma unroll
      for (int i = 0; i < 4; ++i)
        #pragma unroll
        for (int j = 0; j < 4; ++j)
          acc[i][j] = __builtin_amdgcn_mfma_f32_16x16x32_bf16(af[i], bfr[j], acc[i][j], 0, 0, 0);
    }
    __syncthreads();
  }
  const int cr = (l >> 4) << 2, cc = l & 15;
  #pragma unroll
  for (int i = 0; i < 4; ++i) {
    #pragma unroll
    for (int j = 0; j < 4; ++j) {
      const int col = n0 + wn + j*16 + cc;
      #pragma unroll
      for (int r = 0; r < 4; ++r) {
        const int row = m0 + wm + i*16 + cr + r;
        const float bb = bias_row ? bias[row] : bias[col];
        C[(size_t)row * ldc + col] = f2b(acc[i][j][r] + bb);
      }
    }
  }
}

// ---------- scores GEMM: E[m,n] = exp( (K[m,:].Q[n,:]) * SCALE ), f32 out ----------
__launch_bounds__(256)
__global__ void score_gemm(const u16* __restrict__ Kb, const u16* __restrict__ Qb,
                           float* __restrict__ E) {
  __shared__ __align__(16) u16 Al[128*64];
  __shared__ __align__(16) u16 Bl[128*64];
  const int t = threadIdx.x, w = t >> 6, l = t & 63;
  const int bh = blockIdx.z, b = bh >> 3, h = bh & 7;
  const u16* A  = Kb + (size_t)b * Nn * Dd;                  // lda 512
  const u16* Bm = Qb + (size_t)b * Nn * BNrows + h * Dd;     // ldb 4096
  float* C = E + (size_t)bh * Nn * Nn;                       // ldc 2048
  const int m0 = blockIdx.y * 128, n0 = blockIdx.x * 128;
  const int wm = (w >> 1) * 64, wn = (w & 1) * 64;
  const int srow = l >> 3, scol = (l & 7) * 8;
  f4 acc[4][4] = {};
  for (int k0 = 0; k0 < 512; k0 += 64) {
    #pragma unroll
    for (int j = 0; j < 4; ++j) {
      const int chunk = (w << 2) + j;
      const int row = (chunk << 3) + srow;
      gload_lds16(A  + (size_t)(m0 + row) * Dd      + (k0 + scol), &Al[chunk << 9]);
      gload_lds16(Bm + (size_t)(n0 + row) * BNrows  + (k0 + scol), &Bl[chunk << 9]);
    }
    __syncthreads();
    #pragma unroll
    for (int ks = 0; ks < 64; ks += 32) {
      short8 af[4], bfr[4];
      #pragma unroll
      for (int i = 0; i < 4; ++i)
        af[i] = *(const short8*)&Al[(wm + i*16 + (l & 15)) * 64 + ks + ((l >> 4) << 3)];
      #pragma unroll
      for (int j = 0; j < 4; ++j)
        bfr[j] = *(const short8*)&Bl[(wn + j*16 + (l & 15)) * 64 + ks + ((l >> 4) << 3)];
      #pragma unroll
      for (int i = 0; i < 4; ++i)
        #pragma unroll
        for (int j = 0; j < 4; ++j)
          acc[i][j] = __builtin_amdgcn_mfma_f32_16x16x32_bf16(af[i], bfr[j], acc[i][j], 0, 0, 0);
    }
    __syncthreads();
  }
  const int cr = (l >> 4) << 2, cc = l & 15;
  #pragma unroll
  for (int i = 0; i < 4; ++i) {
    #pragma unroll
    for (int j = 0; j < 4; ++j) {
      const int col = n0 + wn + j*16 + cc;
      #pragma unroll
      for (int r = 0; r < 4; ++r) {
        const int row = m0 + wm + i*16 + cr + r;
        C[(size_t)row * Nn + col] = __expf(acc[i][j][r] * SCALE);
      }
    }
  }
}

// ---------- column sums of exp values: s[bh][n] = sum_m E[bh][m][n] ----------
__global__ void colsum_kernel(const float* __restrict__ E, float* __restrict__ s) {
  const int n = blockIdx.x * 256 + threadIdx.x;
  const int mc = blockIdx.y, bh = blockIdx.z;
  const float* p = E + (size_t)bh * Nn * Nn + (size_t)mc * 256 * Nn + n;
  float a0=0,a1=0,a2=0,a3=0,a4=0,a5=0,a6=0,a7=0;
  for (int m = 0; m < 256; m += 8) {
    a0 += p[(size_t)(m+0)*Nn]; a1 += p[(size_t)(m+1)*Nn];
    a2 += p[(size_t)(m+2)*Nn]; a3 += p[(size_t)(m+3)*Nn];
    a4 += p[(size_t)(m+4)*Nn]; a5 += p[(size_t)(m+5)*Nn];
    a6 += p[(size_t)(m+6)*Nn]; a7 += p[(size_t)(m+7)*Nn];
  }
  atomicAdd(&s[bh * Nn + n], ((a0+a1)+(a2+a3)) + ((a4+a5)+(a6+a7)));
}

// ---------- output GEMM: O[m,v] = sum_n (E[m,n]*rs[n]) * Vt[v,n] ----------
// BM=64, BN=512 (full), BK=32. Fuses the softmax normalize: writes At back in place.
__launch_bounds__(256)
__global__ void out_gemm(float* __restrict__ E, const u16* __restrict__ Vt,
                         const float* __restrict__ rs, float* __restrict__ O) {
  __shared__ __align__(16) u16 Al[64*32];    // 4KB  (At tile, bf16)
  __shared__ __align__(16) u16 Bl[512*32];   // 32KB (Vt tile, bf16)
  const int t = threadIdx.x, w = t >> 6, l = t & 63;
  const int mb = blockIdx.x, bh = blockIdx.y, b = bh >> 3;
  float* Ep = E + (size_t)bh * Nn * Nn + (size_t)mb * 64 * Nn;
  const float* rsp = rs + bh * Nn;
  const u16* Vp = Vt + (size_t)b * Nn;       // Vt is [512][4096], col offset b*2048
  const int wv = w << 7;                     // wave's 128-wide v slice
  const int am = t >> 2, an8 = (t & 3) << 3; // A-stage: 64 rows x 32 cols f32
  const int bvr = l >> 2, bcol = (l & 3) << 3;
  f4 acc[4][8] = {};
  for (int k0 = 0; k0 < Nn; k0 += 32) {
    // B stage: 32KB = 32 chunks, 8 per wave, async direct-to-LDS
    #pragma unroll
    for (int j = 0; j < 8; ++j) {
      const int chunk = (w << 3) + j;
      const int vrow = (chunk << 4) + bvr;
      gload_lds16(Vp + (size_t)vrow * BNrows + k0 + bcol, &Bl[chunk << 9]);
    }
    // A stage: load exp f32, normalize, write At back, convert to bf16 -> LDS
    float* ap = Ep + (size_t)am * Nn + k0 + an8;
    f4 x0 = *(const f4*)ap;
    f4 x1 = *(const f4*)(ap + 4);
    const f4 r0 = *(const f4*)(rsp + k0 + an8);
    const f4 r1 = *(const f4*)(rsp + k0 + an8 + 4);
    x0 *= r0; x1 *= r1;
    *(f4*)ap = x0; *(f4*)(ap + 4) = x1;      // normalized At (final output values)
    short8 ab;
    ab[0]=(short)f2b(x0[0]); ab[1]=(short)f2b(x0[1]); ab[2]=(short)f2b(x0[2]); ab[3]=(short)f2b(x0[3]);
    ab[4]=(short)f2b(x1[0]); ab[5]=(short)f2b(x1[1]); ab[6]=(short)f2b(x1[2]); ab[7]=(short)f2b(x1[3]);
    *(short8*)&Al[am * 32 + an8] = ab;
    __syncthreads();
    short8 af[4];
    #pragma unroll
    for (int i = 0; i < 4; ++i)
      af[i] = *(const short8*)&Al[(i*16 + (l & 15)) * 32 + ((l >> 4) << 3)];
    #pragma unroll
    for (int j = 0; j < 8; ++j) {
      const short8 bfj = *(const short8*)&Bl[(wv + j*16 + (l & 15)) * 32 + ((l >> 4) << 3)];
      #pragma unroll
      for (int i = 0; i < 4; ++i)
        acc[i][j] = __builtin_amdgcn_mfma_f32_16x16x32_bf16(af[i], bfj, acc[i][j], 0, 0, 0);
    }
    __syncthreads();
  }
  float* Op = O + (size_t)bh * Nn * Dd + (size_t)mb * 64 * Dd;
  #pragma unroll
  for (int i = 0; i < 4; ++i)
    #pragma unroll
    for (int j = 0; j < 8; ++j)
      #pragma unroll
      for (int r = 0; r < 4; ++r)
        Op[(size_t)(i*16 + ((l >> 4) << 2) + r) * Dd + (wv + j*16 + (l & 15))] = acc[i][j][r];
}

// ---------- launch ----------
extern "C" void kernel_launch(void* const* d_in, const int* in_sizes, int n_in,
                              void* d_out, int out_size, void* d_ws, size_t ws_size,
                              hipStream_t stream) {
  const float* x  = (const float*)d_in[0];
  const float* Wq = (const float*)d_in[1];
  const float* bq = (const float*)d_in[2];
  const float* Wk = (const float*)d_in[3];
  const float* bk = (const float*)d_in[4];
  const float* Wv = (const float*)d_in[5];
  const float* bv = (const float*)d_in[6];

  // workspace layout (bf16 buffers + softmax sums), ~51.6 MB
  u16* xb  = (u16*)d_ws;                         // [4096][512]
  u16* Wqb = xb  + (size_t)4096 * 512;           // [4096][512] (H*DK x D)
  u16* Wkb = Wqb + (size_t)4096 * 512;           // [512][512]
  u16* Wvb = Wkb + (size_t)512 * 512;            // [512][512]
  u16* Qb  = Wvb + (size_t)512 * 512;            // [4096][4096] (rows b*N+n, cols h*DK+k)
  u16* Kb  = Qb  + (size_t)4096 * 4096;          // [4096][512]
  u16* Vtb = Kb  + (size_t)4096 * 512;           // [512][4096] (V transposed)
  float* ssum = (float*)(Vtb + (size_t)4096 * 512); // [16][2048]
  float* rs   = ssum + 16 * 2048;                   // [16][2048]

  float* Eo = (float*)d_out;                     // At region [16][2048][2048]
  float* Oo = Eo + (size_t)16 * 2048 * 2048;     // out region [16][2048][512]

  cvt_kernel<<<1024, 256, 0, stream>>>(x,  xb,  262144);
  cvt_kernel<<<1024, 256, 0, stream>>>(Wq, Wqb, 262144);
  cvt_kernel<<<128,  256, 0, stream>>>(Wk, Wkb, 32768);
  cvt_kernel<<<128,  256, 0, stream>>>(Wv, Wvb, 32768);
  zero_kernel<<<128, 256, 0, stream>>>(ssum, 32768);

  // Q: x @ Wq^T + bq(col) ; K: x @ Wk^T + bk(col) ; Vt: Wv @ x^T + bv(row)
  proj_gemm<<<dim3(32, 32), 256, 0, stream>>>(xb, 512, Wqb, 512, bq, 0, Qb, 4096);
  proj_gemm<<<dim3(4, 32),  256, 0, stream>>>(xb, 512, Wkb, 512, bk, 0, Kb, 512);
  proj_gemm<<<dim3(32, 4),  256, 0, stream>>>(Wvb, 512, xb, 512, bv, 1, Vtb, 4096);

  score_gemm<<<dim3(16, 16, 16), 256, 0, stream>>>(Kb, Qb, Eo);
  colsum_kernel<<<dim3(8, 8, 16), 256, 0, stream>>>(Eo, ssum);
  recip_kernel<<<128, 256, 0, stream>>>(ssum, rs, 32768);
  out_gemm<<<dim3(32, 16), 256, 0, stream>>>(Eo, Vtb, rs, Oo);
}

// Round 2
// 687.245 us; speedup vs baseline: 1.1234x; 1.1234x over previous
//
#include <hip/hip_runtime.h>
#include <stdint.h>

typedef __attribute__((ext_vector_type(8))) short short8;
typedef __attribute__((ext_vector_type(4))) float f4;
typedef unsigned short u16;

// Problem dims (fixed)
#define Nn 2048          // seq len
#define Dd 512           // model dim = DK = DV
#define Hh 8             // heads
#define BNrows 4096      // B*N
#define SCALE 0.044194173824159216f  // 1/sqrt(512)

// ---------- helpers ----------
__device__ __forceinline__ u16 f2b(float f) {   // f32 -> bf16 RNE
  union { float f; uint32_t u; } c; c.f = f;
  uint32_t u = c.u;
  u += 0x7fffu + ((u >> 16) & 1u);
  return (u16)(u >> 16);
}

__device__ __forceinline__ void gload_lds16(const void* g, void* l) {
  // async global->LDS, 16B per lane; LDS dest = wave-uniform base + lane*16
  __builtin_amdgcn_global_load_lds((const __attribute__((address_space(1))) void*)g,
                                   (__attribute__((address_space(3))) void*)l, 16, 0, 0);
}

// ---------- prep: all f32->bf16 converts + ssum zeroing, one dispatch ----------
// segments (in short8 groups): x 262144 | Wq 262144 | Wk 32768 | Wv 32768 ; then 32768 zeros
__global__ void prep_kernel(const float* __restrict__ x,  u16* __restrict__ xb,
                            const float* __restrict__ Wq, u16* __restrict__ Wqb,
                            const float* __restrict__ Wk, u16* __restrict__ Wkb,
                            const float* __restrict__ Wv, u16* __restrict__ Wvb,
                            float* __restrict__ ssum) {
  const int g = blockIdx.x * 256 + threadIdx.x;
  if (g >= 589824) {                       // zero segment
    ssum[g - 589824] = 0.0f;
    return;
  }
  const float* src; u16* dst; int i;
  if (g < 262144)      { src = x;  dst = xb;  i = g; }
  else if (g < 524288) { src = Wq; dst = Wqb; i = g - 262144; }
  else if (g < 557056) { src = Wk; dst = Wkb; i = g - 524288; }
  else                 { src = Wv; dst = Wvb; i = g - 557056; }
  const f4* s4 = (const f4*)src;
  f4 a = s4[2*i], b = s4[2*i+1];
  short8 o;
  o[0]=(short)f2b(a[0]); o[1]=(short)f2b(a[1]); o[2]=(short)f2b(a[2]); o[3]=(short)f2b(a[3]);
  o[4]=(short)f2b(b[0]); o[5]=(short)f2b(b[1]); o[6]=(short)f2b(b[2]); o[7]=(short)f2b(b[3]);
  ((short8*)dst)[i] = o;
}

__global__ void recip_kernel(const float* __restrict__ s, float* __restrict__ rs, int n) {
  int i = blockIdx.x * 256 + threadIdx.x;
  if (i < n) rs[i] = 1.0f / s[i];
}

// ---------- fused projections: Q (1024 blocks) | K (128) | Vt (128), one dispatch ----------
// C[m,n] = sum_k A[m,k]*B[n,k] + bias, bf16 out. 128x128 tile, BK=64, 4 waves.
__launch_bounds__(256)
__global__ void proj_all(const u16* __restrict__ xb, const u16* __restrict__ Wqb,
                         const u16* __restrict__ Wkb, const u16* __restrict__ Wvb,
                         const float* __restrict__ bq, const float* __restrict__ bk,
                         const float* __restrict__ bv,
                         u16* __restrict__ Qb, u16* __restrict__ Kb, u16* __restrict__ Vtb) {
  __shared__ __align__(16) u16 Al[128*64];
  __shared__ __align__(16) u16 Bl[128*64];
  const int bid = blockIdx.x;
  const u16 *A, *Bm; u16* C;
  const float* bias;
  int lda, ldb, ldc, bias_row, m0, n0;
  if (bid < 1024) {            // Q: x[4096x512] @ Wq[4096x512]^T -> Qb[4096x4096]
    A = xb; lda = 512; Bm = Wqb; ldb = 512; bias = bq; bias_row = 0;
    C = Qb; ldc = 4096; n0 = (bid & 31) * 128; m0 = (bid >> 5) * 128;
  } else if (bid < 1152) {     // K: x @ Wk[512x512]^T -> Kb[4096x512]
    const int id = bid - 1024;
    A = xb; lda = 512; Bm = Wkb; ldb = 512; bias = bk; bias_row = 0;
    C = Kb; ldc = 512; n0 = (id & 3) * 128; m0 = (id >> 2) * 128;
  } else {                     // Vt: Wv[512x512] @ x^T -> Vtb[512x4096]
    const int id = bid - 1152;
    A = Wvb; lda = 512; Bm = xb; ldb = 512; bias = bv; bias_row = 1;
    C = Vtb; ldc = 4096; n0 = (id & 31) * 128; m0 = (id >> 5) * 128;
  }
  const int t = threadIdx.x, w = t >> 6, l = t & 63;
  const int wm = (w >> 1) * 64, wn = (w & 1) * 64;
  const int srow = l >> 3, scol = (l & 7) * 8;
  f4 acc[4][4] = {};
  for (int k0 = 0; k0 < 512; k0 += 64) {
    #pragma unroll
    for (int j = 0; j < 4; ++j) {
      const int chunk = (w << 2) + j;       // 16 chunks of 1KB per tile
      const int row = (chunk << 3) + srow;
      gload_lds16(A  + (size_t)(m0 + row) * lda + (k0 + scol), &Al[chunk << 9]);
      gload_lds16(Bm + (size_t)(n0 + row) * ldb + (k0 + scol), &Bl[chunk << 9]);
    }
    __syncthreads();
    #pragma unroll
    for (int ks = 0; ks < 64; ks += 32) {
      short8 af[4], bfr[4];
      #pragma unroll
      for (int i = 0; i < 4; ++i)
        af[i] = *(const short8*)&Al[(wm + i*16 + (l & 15)) * 64 + ks + ((l >> 4) << 3)];
      #pragma unroll
      for (int j = 0; j < 4; ++j)
        bfr[j] = *(const short8*)&Bl[(wn + j*16 + (l & 15)) * 64 + ks + ((l >> 4) << 3)];
      #pragma unroll
      for (int i = 0; i < 4; ++i)
        #pragma unroll
        for (int j = 0; j < 4; ++j)
          acc[i][j] = __builtin_amdgcn_mfma_f32_16x16x32_bf16(af[i], bfr[j], acc[i][j], 0, 0, 0);
    }
    __syncthreads();
  }
  const int cr = (l >> 4) << 2, cc = l & 15;
  #pragma unroll
  for (int i = 0; i < 4; ++i) {
    #pragma unroll
    for (int j = 0; j < 4; ++j) {
      const int col = n0 + wn + j*16 + cc;
      #pragma unroll
      for (int r = 0; r < 4; ++r) {
        const int row = m0 + wm + i*16 + cr + r;
        const float bb = bias_row ? bias[row] : bias[col];
        C[(size_t)row * ldc + col] = f2b(acc[i][j][r] + bb);
      }
    }
  }
}

// ---------- scores GEMM: E[m,n] = exp((K[m,:].Q[n,:])*SCALE), f32 out, fused col-sums ----------
__launch_bounds__(256)
__global__ void score_gemm(const u16* __restrict__ Kb, const u16* __restrict__ Qb,
                           float* __restrict__ E, float* __restrict__ ssum) {
  __shared__ __align__(16) u16 Al[128*64];
  __shared__ __align__(16) u16 Bl[128*64];
  const int t = threadIdx.x, w = t >> 6, l = t & 63;
  const int bh = blockIdx.z, b = bh >> 3, h = bh & 7;
  const u16* A  = Kb + (size_t)b * Nn * Dd;                  // lda 512
  const u16* Bm = Qb + (size_t)b * Nn * BNrows + h * Dd;     // ldb 4096
  float* C = E + (size_t)bh * Nn * Nn;                       // ldc 2048
  const int m0 = blockIdx.y * 128, n0 = blockIdx.x * 128;
  const int wm = (w >> 1) * 64, wn = (w & 1) * 64;
  const int srow = l >> 3, scol = (l & 7) * 8;
  f4 acc[4][4] = {};
  for (int k0 = 0; k0 < 512; k0 += 64) {
    #pragma unroll
    for (int j = 0; j < 4; ++j) {
      const int chunk = (w << 2) + j;
      const int row = (chunk << 3) + srow;
      gload_lds16(A  + (size_t)(m0 + row) * Dd      + (k0 + scol), &Al[chunk << 9]);
      gload_lds16(Bm + (size_t)(n0 + row) * BNrows  + (k0 + scol), &Bl[chunk << 9]);
    }
    __syncthreads();
    #pragma unroll
    for (int ks = 0; ks < 64; ks += 32) {
      short8 af[4], bfr[4];
      #pragma unroll
      for (int i = 0; i < 4; ++i)
        af[i] = *(const short8*)&Al[(wm + i*16 + (l & 15)) * 64 + ks + ((l >> 4) << 3)];
      #pragma unroll
      for (int j = 0; j < 4; ++j)
        bfr[j] = *(const short8*)&Bl[(wn + j*16 + (l & 15)) * 64 + ks + ((l >> 4) << 3)];
      #pragma unroll
      for (int i = 0; i < 4; ++i)
        #pragma unroll
        for (int j = 0; j < 4; ++j)
          acc[i][j] = __builtin_amdgcn_mfma_f32_16x16x32_bf16(af[i], bfr[j], acc[i][j], 0, 0, 0);
    }
    __syncthreads();
  }
  const int cr = (l >> 4) << 2, cc = l & 15;
  float psum[4] = {0.f, 0.f, 0.f, 0.f};
  #pragma unroll
  for (int i = 0; i < 4; ++i) {
    #pragma unroll
    for (int j = 0; j < 4; ++j) {
      const int col = n0 + wn + j*16 + cc;
      #pragma unroll
      for (int r = 0; r < 4; ++r) {
        const int row = m0 + wm + i*16 + cr + r;
        const float e = __expf(acc[i][j][r] * SCALE);
        C[(size_t)row * Nn + col] = e;
        psum[j] += e;
      }
    }
  }
  // column partial sums: reduce over the 4 row-lane groups (l^16, l^32), then atomic
  float* sp = ssum + bh * Nn + n0 + wn;
  #pragma unroll
  for (int j = 0; j < 4; ++j) {
    float p = psum[j];
    p += __shfl_xor(p, 16);
    p += __shfl_xor(p, 32);
    if (l < 16) atomicAdd(&sp[j*16 + l], p);
  }
}

// ---------- output GEMM: O[m,v] = sum_n (E[m,n]*rs[n]) * Vt[v,n] ----------
// BM=64, BN=512 (full), BK=32. Fuses softmax normalize: writes At back in place.
__launch_bounds__(256)
__global__ void out_gemm(float* __restrict__ E, const u16* __restrict__ Vt,
                         const float* __restrict__ rs, float* __restrict__ O) {
  __shared__ __align__(16) u16 Al[64*32];    // 4KB  (At tile, bf16)
  __shared__ __align__(16) u16 Bl[512*32];   // 32KB (Vt tile, bf16)
  const int t = threadIdx.x, w = t >> 6, l = t & 63;
  const int mb = blockIdx.x, bh = blockIdx.y, b = bh >> 3;
  float* Ep = E + (size_t)bh * Nn * Nn + (size_t)mb * 64 * Nn;
  const float* rsp = rs + bh * Nn;
  const u16* Vp = Vt + (size_t)b * Nn;       // Vt is [512][4096], col offset b*2048
  const int wv = w << 7;                     // wave's 128-wide v slice
  const int am = t >> 2, an8 = (t & 3) << 3; // A-stage: 64 rows x 32 cols f32
  const int bvr = l >> 2, bcol = (l & 3) << 3;
  f4 acc[4][8] = {};
  for (int k0 = 0; k0 < Nn; k0 += 32) {
    // B stage: 32KB = 32 chunks, 8 per wave, async direct-to-LDS
    #pragma unroll
    for (int j = 0; j < 8; ++j) {
      const int chunk = (w << 3) + j;
      const int vrow = (chunk << 4) + bvr;
      gload_lds16(Vp + (size_t)vrow * BNrows + k0 + bcol, &Bl[chunk << 9]);
    }
    // A stage: load exp f32, normalize, write At back, convert to bf16 -> LDS
    float* ap = Ep + (size_t)am * Nn + k0 + an8;
    f4 x0 = *(const f4*)ap;
    f4 x1 = *(const f4*)(ap + 4);
    const f4 r0 = *(const f4*)(rsp + k0 + an8);
    const f4 r1 = *(const f4*)(rsp + k0 + an8 + 4);
    x0 *= r0; x1 *= r1;
    *(f4*)ap = x0; *(f4*)(ap + 4) = x1;      // normalized At (final output values)
    short8 ab;
    ab[0]=(short)f2b(x0[0]); ab[1]=(short)f2b(x0[1]); ab[2]=(short)f2b(x0[2]); ab[3]=(short)f2b(x0[3]);
    ab[4]=(short)f2b(x1[0]); ab[5]=(short)f2b(x1[1]); ab[6]=(short)f2b(x1[2]); ab[7]=(short)f2b(x1[3]);
    *(short8*)&Al[am * 32 + an8] = ab;
    __syncthreads();
    short8 af[4];
    #pragma unroll
    for (int i = 0; i < 4; ++i)
      af[i] = *(const short8*)&Al[(i*16 + (l & 15)) * 32 + ((l >> 4) << 3)];
    #pragma unroll
    for (int j = 0; j < 8; ++j) {
      const short8 bfj = *(const short8*)&Bl[(wv + j*16 + (l & 15)) * 32 + ((l >> 4) << 3)];
      #pragma unroll
      for (int i = 0; i < 4; ++i)
        acc[i][j] = __builtin_amdgcn_mfma_f32_16x16x32_bf16(af[i], bfj, acc[i][j], 0, 0, 0);
    }
    __syncthreads();
  }
  float* Op = O + (size_t)bh * Nn * Dd + (size_t)mb * 64 * Dd;
  #pragma unroll
  for (int i = 0; i < 4; ++i)
    #pragma unroll
    for (int j = 0; j < 8; ++j)
      #pragma unroll
      for (int r = 0; r < 4; ++r)
        Op[(size_t)(i*16 + ((l >> 4) << 2) + r) * Dd + (wv + j*16 + (l & 15))] = acc[i][j][r];
}

// ---------- launch ----------
extern "C" void kernel_launch(void* const* d_in, const int* in_sizes, int n_in,
                              void* d_out, int out_size, void* d_ws, size_t ws_size,
                              hipStream_t stream) {
  const float* x  = (const float*)d_in[0];
  const float* Wq = (const float*)d_in[1];
  const float* bq = (const float*)d_in[2];
  const float* Wk = (const float*)d_in[3];
  const float* bk = (const float*)d_in[4];
  const float* Wv = (const float*)d_in[5];
  const float* bv = (const float*)d_in[6];

  // workspace layout (bf16 buffers + softmax sums), ~51.6 MB
  u16* xb  = (u16*)d_ws;                         // [4096][512]
  u16* Wqb = xb  + (size_t)4096 * 512;           // [4096][512] (H*DK x D)
  u16* Wkb = Wqb + (size_t)4096 * 512;           // [512][512]
  u16* Wvb = Wkb + (size_t)512 * 512;            // [512][512]
  u16* Qb  = Wvb + (size_t)512 * 512;            // [4096][4096] (rows b*N+n, cols h*DK+k)
  u16* Kb  = Qb  + (size_t)4096 * 4096;          // [4096][512]
  u16* Vtb = Kb  + (size_t)4096 * 512;           // [512][4096] (V transposed)
  float* ssum = (float*)(Vtb + (size_t)4096 * 512); // [16][2048]
  float* rs   = ssum + 16 * 2048;                   // [16][2048]

  float* Eo = (float*)d_out;                     // At region [16][2048][2048]
  float* Oo = Eo + (size_t)16 * 2048 * 2048;     // out region [16][2048][512]

  prep_kernel<<<2432, 256, 0, stream>>>(x, xb, Wq, Wqb, Wk, Wkb, Wv, Wvb, ssum);
  proj_all<<<1280, 256, 0, stream>>>(xb, Wqb, Wkb, Wvb, bq, bk, bv, Qb, Kb, Vtb);
  score_gemm<<<dim3(16, 16, 16), 256, 0, stream>>>(Kb, Qb, Eo, ssum);
  recip_kernel<<<128, 256, 0, stream>>>(ssum, rs, 32768);
  out_gemm<<<dim3(32, 16), 256, 0, stream>>>(Eo, Vtb, rs, Oo);
}